// Round 16
// baseline (195.143 us; speedup 1.0000x reference)
//
#include <hip/hip_runtime.h>
#include <hip/hip_bf16.h>
#include <math.h>

typedef unsigned short U16;
typedef unsigned int U32;
typedef __attribute__((ext_vector_type(8))) short bf8;        // 8 x bf16 (MFMA A/B frag)
typedef __attribute__((ext_vector_type(4))) float f4;         // MFMA C/D frag
typedef __attribute__((ext_vector_type(4))) unsigned short u16x4;

#define AS1 __attribute__((address_space(1)))
#define AS3 __attribute__((address_space(3)))

// ---- constants ----
#define BSZ   256
#define NTOK  196
#define NQ    49
#define INDIM 384
#define OUTD  512
#define NH    12
#define DV    64
#define DHD   768
#define KVH   1152
#define NPADR 224      // LDS token rows (196 real + 28 clamped copies of row 195, masked)

__device__ inline U16 f2bf(float f){
    __hip_bfloat16 h = __float2bfloat16(f);
    return *(U16*)&h;
}
__device__ inline f4 f4zero(){ f4 z; z[0]=0.f; z[1]=0.f; z[2]=0.f; z[3]=0.f; return z; }

// ---------------- single prep kernel: x cast | weight casts | bias + BN ----------------
#define XC_N   (BSZ*NTOK*INDIM/8)    // 2,408,448 slots
#define XC_BLK (XC_N/256)            // 9408 (exact)
#define W1C (KVH*INDIM/8)            // 55296
#define W2C (INDIM*INDIM/8)          // 18432
#define W3C (OUTD*DHD/8)             // 49152
#define WC_N   (W1C+W2C+W3C)         // 122880
#define WC_BLK (WC_N/256)            // 480 (exact)
#define BIAS_N   (NH*NQ*NTOK)        // 115248
#define BIAS_BLK ((BIAS_N+255)/256)  // 451
#define BN_BLK   ((KVH+INDIM+OUTD)/256)  // 8
__global__ void k_prep(const float* __restrict__ x, U16* __restrict__ x_bf,
                       const float* __restrict__ w1, const float* __restrict__ w2,
                       const float* __restrict__ w3, U16* __restrict__ o1,
                       U16* __restrict__ o2, U16* __restrict__ o3,
                       const float* __restrict__ ab, const int* __restrict__ idxs, int n_off,
                       const float* __restrict__ g1, const float* __restrict__ b1,
                       const float* __restrict__ m1, const float* __restrict__ v1,
                       const float* __restrict__ g2, const float* __restrict__ b2,
                       const float* __restrict__ m2, const float* __restrict__ v2,
                       const float* __restrict__ g3, const float* __restrict__ b3,
                       const float* __restrict__ m3, const float* __restrict__ v3,
                       float* __restrict__ s1, float* __restrict__ bo1,
                       float* __restrict__ s2, float* __restrict__ bo2,
                       float* __restrict__ s3, float* __restrict__ bo3,
                       float* __restrict__ bias_out){
    const int blk = blockIdx.x;
    const int tid = threadIdx.x;
    if (blk < XC_BLK){
        int i = blk*256 + tid;                 // 8-elem slot of x
        const float* p = x + (size_t)i*8;
        U16 o[8];
#pragma unroll
        for (int j=0;j<8;++j) o[j] = f2bf(p[j]);
        *(bf8*)(x_bf + (size_t)i*8) = *(const bf8*)o;
    } else if (blk < XC_BLK + WC_BLK){
        int i = (blk-XC_BLK)*256 + tid;
        const float* p; U16* o;
        if (i < W1C){ p = w1 + (size_t)i*8; o = o1 + (size_t)i*8; }
        else if (i < W1C+W2C){ int k=i-W1C; p = w2 + (size_t)k*8; o = o2 + (size_t)k*8; }
        else { int k=i-W1C-W2C; p = w3 + (size_t)k*8; o = o3 + (size_t)k*8; }
        U16 t[8];
#pragma unroll
        for (int j=0;j<8;++j) t[j] = f2bf(p[j]);
        *(bf8*)o = *(const bf8*)t;
    } else if (blk < XC_BLK + WC_BLK + BIAS_BLK){
        int i = (blk-XC_BLK-WC_BLK)*256 + tid;
        if (i < BIAS_N){
            int h = i / (NQ*NTOK);
            int qk = i - h*(NQ*NTOK);
            bias_out[i] = ab[h*n_off + idxs[qk]];
        }
    } else {
        int i = (blk-XC_BLK-WC_BLK-BIAS_BLK)*256 + tid;
        const float *g,*b,*m,*v; float *so,*bo; int k;
        if (i < KVH){ g=g1;b=b1;m=m1;v=v1;so=s1;bo=bo1;k=i; }
        else if (i < KVH+INDIM){ g=g2;b=b2;m=m2;v=v2;so=s2;bo=bo2;k=i-KVH; }
        else { g=g3;b=b3;m=m3;v=v3;so=s3;bo=bo3;k=i-KVH-INDIM; }
        float s = g[k] / sqrtf(v[k] + 1e-5f);
        so[k] = s;
        bo[k] = b[k] - m[k]*s;
    }
}

// ---------------- fused kvq-GEMM + attention: 1 head/block ----------------
// GEMM: C[224 rows][128 cols = k(32)|v(64)|q-weights(32)], BK=32, 12 K-steps.
// q computed for ALL rows; epilogue scatters subsampled rows (n even, n%28<14) into QL.
// LDS = 22528 u16 = 45,056 B -> 3 blocks/CU.
//   staging: A0 [0,7168) A1 [7168,14336) B0 [14336,18432) B1 [18432,22528)
//   post-GEMM (aliases dead staging):
//     VL [0,12800):      [nch<=24][64 d][8] (writes guarded n0<200)
//     KL [12800,19968):  [4 dch][224 n][8]
//     QL [19968,22016):  [4 dch][64 qg][8]
//     PV reads VL nch 25..27 (n>=200) overlap KL -> finite garbage x P=0 = 0.
// P never hits LDS: cross-lane __shfl transpose into PV A-frags (packed on the fly).
#define KLO 12800
#define QLO 19968
__global__ __launch_bounds__(256,2) void k_fused(
    const U16* __restrict__ xbf, const U16* __restrict__ kvw, const U16* __restrict__ qw,
    const float* __restrict__ skv, const float* __restrict__ bkv,
    const float* __restrict__ sq,  const float* __restrict__ bq,
    const float* __restrict__ biasf, U16* __restrict__ aout)
{
    __shared__ U16 smem[22528];   // 45,056 B
    const int hw = blockIdx.x;
    const int bh = (hw & 7)*384 + (hw >> 3);   // bijective XCD swizzle (3072 = 8*384)
    const int b = bh / NH, h = bh - b*NH;
    const int tid = threadIdx.x, lane = tid & 63, w = tid >> 6;
    const int wm = w & 1, wn = w >> 1;
    const int l15 = lane & 15, oct = lane >> 4;

    U16* Ab[2] = { smem + 0,     smem + 7168 };
    U16* Bb[2] = { smem + 14336, smem + 18432 };

    // A: 896 chunks (slot = kch*224 + row); threads 0..127 take a 4th; row clamped <196
    U32 aoff[4];
#pragma unroll
    for (int c=0;c<3;++c){
        int s = c*256 + tid;
        int ach = s / NPADR, ar = s - ach*NPADR;
        int row = (ar < NTOK) ? ar : (NTOK-1);
        aoff[c] = (U32)(b*NTOK + row)*INDIM + ach*8;
    }
    {
        int s = 768 + (tid & 127);
        int ach = s / NPADR, ar = s - ach*NPADR;
        int row = (ar < NTOK) ? ar : (NTOK-1);
        aoff[3] = (U32)(b*NTOK + row)*INDIM + ach*8;
    }
    // B: 512 chunks (slot = kch*128 + row); rows 0-95 = kv weights, 96-127 = q weights
    const U16* bbase[2];
#pragma unroll
    for (int c=0;c<2;++c){
        int s = c*256 + tid;
        int bc = s >> 7, br = s & 127;
        bbase[c] = (br < 96) ? kvw + ((size_t)(h*96 + br))*INDIM + bc*8
                             : qw  + ((size_t)(h*32 + (br-96)))*INDIM + bc*8;
    }

    f4 acc[7][4];
#pragma unroll
    for (int i=0;i<7;++i)
#pragma unroll
        for (int j=0;j<4;++j) acc[i][j] = f4zero();

#define STAGE(buf, kb) do{ \
    _Pragma("unroll") \
    for (int c=0;c<3;++c) \
        __builtin_amdgcn_global_load_lds((const AS1 U32*)(xbf + aoff[c] + (kb)), \
            (AS3 U32*)(Ab[buf] + (c*256+tid)*8), 16, 0, 0); \
    if (tid < 128) \
        __builtin_amdgcn_global_load_lds((const AS1 U32*)(xbf + aoff[3] + (kb)), \
            (AS3 U32*)(Ab[buf] + (768+tid)*8), 16, 0, 0); \
    _Pragma("unroll") \
    for (int c=0;c<2;++c) \
        __builtin_amdgcn_global_load_lds((const AS1 U32*)(bbase[c] + (kb)), \
            (AS3 U32*)(Bb[buf] + (c*256+tid)*8), 16, 0, 0); \
}while(0)

    // prologue: tile 0 staged and drained
    STAGE(0, 0);
    asm volatile("s_waitcnt vmcnt(0)" ::: "memory");
    __builtin_amdgcn_sched_barrier(0);
    __builtin_amdgcn_s_barrier();
    __builtin_amdgcn_sched_barrier(0);

#pragma unroll
    for (int kt=0; kt<12; ++kt){
        const int cur = kt & 1;
        // stage next tile into the buffer whose reads finished before the last barrier
        if (kt < 11) STAGE(cur^1, (kt+1)*32);
        __builtin_amdgcn_sched_barrier(0);
        bf8 af[7], bfr[4];
#pragma unroll
        for (int i=0;i<7;++i)
            af[i]  = *(const bf8*)(Ab[cur] + (oct*NPADR + wm*112 + i*16 + l15)*8);
#pragma unroll
        for (int j=0;j<4;++j)
            bfr[j] = *(const bf8*)(Bb[cur] + (oct*128 + wn*64 + j*16 + l15)*8);
        __builtin_amdgcn_s_setprio(1);
#pragma unroll
        for (int i=0;i<7;++i)
#pragma unroll
            for (int j=0;j<4;++j)
                acc[i][j] = __builtin_amdgcn_mfma_f32_16x16x32_bf16(af[i], bfr[j], acc[i][j], 0, 0, 0);
        __builtin_amdgcn_s_setprio(0);
        __builtin_amdgcn_sched_barrier(0);
        asm volatile("s_waitcnt vmcnt(0)" ::: "memory");   // next tile landed (drain hidden under MFMA)
        __builtin_amdgcn_s_barrier();                      // ONE barrier per step
        __builtin_amdgcn_sched_barrier(0);
    }
#undef STAGE

    // ---- epilogue: BN fold, scatter acc -> KL / VL / QL (alias dead staging) ----
#pragma unroll
    for (int j=0;j<4;++j){
        const int cc = wn*64 + j*16 + l15;     // [0,128)
        float sc, bi;
        if (cc < 96){ sc = skv[h*96 + cc]; bi = bkv[h*96 + cc]; }
        else        { sc = sq[h*32 + (cc-96)]; bi = bq[h*32 + (cc-96)]; }
#pragma unroll
        for (int i=0;i<7;++i){
            const int n0 = wm*112 + i*16 + oct*4;
            if (cc < 32){
#pragma unroll
                for (int r=0;r<4;++r)
                    smem[KLO + ((cc>>3)*NPADR + n0 + r)*8 + (cc&7)] = f2bf(acc[i][j][r]*sc + bi);
            } else if (cc < 96){
                if (n0 < 200){                 // protect KL overlap (nch>=25 unused: P=0)
                    const int dv = cc - 32;
                    u16x4 pk;
#pragma unroll
                    for (int r=0;r<4;++r) pk[r] = f2bf(acc[i][j][r]*sc + bi);
                    *(u16x4*)(smem + ((n0>>3)*64 + dv)*8 + (oct&1)*4) = pk;
                }
            } else {
                const int dq = cc - 96;
#pragma unroll
                for (int r=0;r<4;++r){
                    const int n = n0 + r;
                    if (n < NTOK && (n & 1) == 0){
                        const int dn = n / 28, nm = n - dn*28;
                        if (nm < 14){
                            const int qg2 = dn*7 + (nm >> 1);
                            smem[QLO + ((dq>>3)*64 + qg2)*8 + (dq&7)] = f2bf(acc[i][j][r]*sc + bi);
                        }
                    }
                }
            }
        }
    }
    __syncthreads();   // K/V/Q visible to all waves

    // ---- attention: 4 waves, each wave 16 q-cols; q read from QL ----
    const int qg = w*16 + l15;
    const bf8 qf = *(const bf8*)(smem + QLO + (oct*64 + qg)*8);  // qg>=49: finite stale bytes, masked

    f4 sacc[14];
#pragma unroll
    for (int mt=0;mt<14;++mt) sacc[mt] = f4zero();
#pragma unroll
    for (int mt=0;mt<14;++mt){
        const bf8 kf = *(const bf8*)(smem + KLO + (oct*NPADR + mt*16 + l15)*8);
        sacc[mt] = __builtin_amdgcn_mfma_f32_16x16x32_bf16(kf, qf, sacc[mt], 0, 0, 0);
    }

    const float scale = 0.17677669529663689f;
    float mx = -1e30f;
#pragma unroll
    for (int mt=0;mt<14;++mt){
        const int n0 = mt*16 + oct*4;
        f4 bi4 = f4zero();
        if (qg < NQ && n0 < NTOK) bi4 = *(const f4*)(biasf + ((size_t)h*NQ + qg)*NTOK + n0);
#pragma unroll
        for (int r=0;r<4;++r){
            float s = (n0 + r < NTOK) ? sacc[mt][r]*scale + bi4[r] : -1e30f;
            sacc[mt][r] = s;
            mx = fmaxf(mx, s);
        }
    }
    mx = fmaxf(mx, __shfl_xor(mx, 16));
    mx = fmaxf(mx, __shfl_xor(mx, 32));

    float sum = 0.f;
#pragma unroll
    for (int mt=0;mt<14;++mt){
#pragma unroll
        for (int r=0;r<4;++r){
            float p = (mt*16 + oct*4 + r < NTOK) ? __expf(sacc[mt][r] - mx) : 0.f;
            sacc[mt][r] = p;
            sum += p;
        }
    }
    sum += __shfl_xor(sum, 16);
    sum += __shfl_xor(sum, 32);
    const float inv = 1.f / sum;

    const int src1 = l15 + (oct & 1)*32;
    const int src2 = src1 + 16;
    const bool hiT = (oct >> 1) != 0;
    f4 pacc[4];
#pragma unroll
    for (int dt=0;dt<4;++dt) pacc[dt] = f4zero();
#pragma unroll
    for (int kt=0;kt<7;++kt){
        const int m0 = 2*kt, m1 = 2*kt+1;
        U32 q00 = (U32)f2bf(sacc[m0][0]*inv) | ((U32)f2bf(sacc[m0][1]*inv) << 16);
        U32 q01 = (U32)f2bf(sacc[m0][2]*inv) | ((U32)f2bf(sacc[m0][3]*inv) << 16);
        U32 q10 = (U32)f2bf(sacc[m1][0]*inv) | ((U32)f2bf(sacc[m1][1]*inv) << 16);
        U32 q11 = (U32)f2bf(sacc[m1][2]*inv) | ((U32)f2bf(sacc[m1][3]*inv) << 16);
        U32 a0 = __shfl(q00, src1), a1 = __shfl(q01, src1);
        U32 c0 = __shfl(q10, src1), c1 = __shfl(q11, src1);
        U32 b0 = __shfl(q00, src2), b1 = __shfl(q01, src2);
        U32 d0 = __shfl(q10, src2), d1 = __shfl(q11, src2);
        union { U32 u[4]; bf8 v; } pu;
        pu.u[0] = hiT ? c0 : a0;
        pu.u[1] = hiT ? c1 : a1;
        pu.u[2] = hiT ? d0 : b0;
        pu.u[3] = hiT ? d1 : b1;
#pragma unroll
        for (int dt=0;dt<4;++dt){
            const bf8 vf = *(const bf8*)(smem + ((kt*4 + oct)*64 + dt*16 + l15)*8);
            pacc[dt] = __builtin_amdgcn_mfma_f32_16x16x32_bf16(pu.v, vf, pacc[dt], 0, 0, 0);
        }
    }

#pragma unroll
    for (int dt=0;dt<4;++dt){
#pragma unroll
        for (int r=0;r<4;++r){
            const int qo2 = w*16 + oct*4 + r;
            if (qo2 < NQ){
                const int d = dt*16 + l15;
                float v = pacc[dt][r];
                float tt = fminf(fmaxf(v + 3.f, 0.f), 6.f);
                aout[((size_t)(b*NQ + qo2))*DHD + h*DV + d] = f2bf(v * tt * (1.f/6.f));
            }
        }
    }
}

// ---------------- proj GEMM 128x64xBK64 (12544 x 512 x 768) -> f32 ----------------
__global__ __launch_bounds__(256,2) void k_proj(
    const U16* __restrict__ A, const U16* __restrict__ Bw,
    const float* __restrict__ s_arr, const float* __restrict__ b_arr,
    float* __restrict__ o32)
{
    __shared__ U16 smem[24576];
    U16* Ab[2] = { smem,          smem + 8192 };
    U16* Bb[2] = { smem + 16384,  smem + 20480 };
    constexpr int NWG = 784, QQ = NWG/8, RR = NWG%8;   // 98, 0
    const int xcd = blockIdx.x & 7, rest = blockIdx.x >> 3;
    const int l = (xcd < RR ? xcd*(QQ+1) : RR*(QQ+1) + (xcd-RR)*QQ) + rest;
    const int mtl = l / 8, ntl = l - mtl*8;
    const int gm0 = mtl*128, gn0 = ntl*64;
    const int tid  = threadIdx.x;
    const int lane = tid & 63;
    const int w    = tid >> 6;
    const int wm   = w & 1, wn = w >> 1;
    const int l15  = lane & 15, oct = lane >> 4;

    f4 acc[4][2];
#pragma unroll
    for (int i=0;i<4;++i)
#pragma unroll
        for (int j=0;j<2;++j) acc[i][j] = f4zero();

    U32 aoff[4], boff[2];
#pragma unroll
    for (int c=0;c<4;++c){
        int slot = c*256 + tid;
        int row = slot & 127, ch = slot >> 7;
        aoff[c] = (U32)(gm0 + row)*DHD + ch*8;
    }
#pragma unroll
    for (int c=0;c<2;++c){
        int slot = c*256 + tid;
        int row = slot & 63, ch = slot >> 6;
        boff[c] = (U32)(gn0 + row)*DHD + ch*8;
    }

#define STG(buf, kb) do{ \
    _Pragma("unroll") \
    for (int c=0;c<4;++c) \
        __builtin_amdgcn_global_load_lds((const AS1 U32*)(A + aoff[c] + (kb)), \
            (AS3 U32*)(Ab[buf] + (c*256+tid)*8), 16, 0, 0); \
    _Pragma("unroll") \
    for (int c=0;c<2;++c) \
        __builtin_amdgcn_global_load_lds((const AS1 U32*)(Bw + boff[c] + (kb)), \
            (AS3 U32*)(Bb[buf] + (c*256+tid)*8), 16, 0, 0); \
}while(0)

    STG(0, 0);

#pragma unroll
    for (int kt=0; kt<12; ++kt){
        const int cur = kt & 1;
        if (kt+1 < 12){
            STG(cur^1, (kt+1)*64);
            asm volatile("s_waitcnt vmcnt(6)" ::: "memory");
        } else {
            asm volatile("s_waitcnt vmcnt(0)" ::: "memory");
        }
        __builtin_amdgcn_sched_barrier(0);
        __builtin_amdgcn_s_barrier();
        __builtin_amdgcn_sched_barrier(0);

#pragma unroll
        for (int kk=0;kk<2;++kk){
            bf8 af[4], bfr[2];
#pragma unroll
            for (int i=0;i<4;++i)
                af[i]  = *(const bf8*)(Ab[cur] + ((kk*4+oct)*128 + wm*64 + i*16 + l15)*8);
#pragma unroll
            for (int j=0;j<2;++j)
                bfr[j] = *(const bf8*)(Bb[cur] + ((kk*4+oct)*64 + wn*32 + j*16 + l15)*8);
            __builtin_amdgcn_s_setprio(1);
#pragma unroll
            for (int i=0;i<4;++i)
#pragma unroll
                for (int j=0;j<2;++j)
                    acc[i][j] = __builtin_amdgcn_mfma_f32_16x16x32_bf16(af[i], bfr[j], acc[i][j], 0, 0, 0);
            __builtin_amdgcn_s_setprio(0);
        }
        __builtin_amdgcn_sched_barrier(0);
        __builtin_amdgcn_s_barrier();
        __builtin_amdgcn_sched_barrier(0);
    }
#undef STG

#pragma unroll
    for (int j=0;j<2;++j){
        const int col = gn0 + wn*32 + j*16 + l15;
        const float sc = s_arr[col];
        const float bi = b_arr[col];
#pragma unroll
        for (int i=0;i<4;++i){
            const int row0 = gm0 + wm*64 + i*16 + oct*4;
#pragma unroll
            for (int r=0;r<4;++r)
                o32[(size_t)(row0+r)*OUTD + col] = acc[i][j][r]*sc + bi;
        }
    }
}

// ---------------- launch ----------------
extern "C" void kernel_launch(void* const* d_in, const int* in_sizes, int n_in,
                              void* d_out, int out_size, void* d_ws, size_t ws_size,
                              hipStream_t stream)
{
    const float* x    = (const float*)d_in[0];
    const float* kv_w = (const float*)d_in[1];
    const float* kv_g = (const float*)d_in[2];
    const float* kv_b = (const float*)d_in[3];
    const float* kv_m = (const float*)d_in[4];
    const float* kv_v = (const float*)d_in[5];
    const float* q_w  = (const float*)d_in[6];
    const float* q_g  = (const float*)d_in[7];
    const float* q_b  = (const float*)d_in[8];
    const float* q_m  = (const float*)d_in[9];
    const float* q_v  = (const float*)d_in[10];
    const float* pr_w = (const float*)d_in[11];
    const float* pr_g = (const float*)d_in[12];
    const float* pr_b = (const float*)d_in[13];
    const float* pr_m = (const float*)d_in[14];
    const float* pr_v = (const float*)d_in[15];
    const float* ab   = (const float*)d_in[16];
    const int*  idxs  = (const int*)d_in[17];
    const int n_off = in_sizes[16] / NH;

    char* ws = (char*)d_ws;
    size_t off = 0;
    auto alloc = [&](size_t bytes)->char*{
        char* p = ws + off; off += (bytes + 255) & ~(size_t)255; return p;
    };
    U16*   x_bf   = (U16*)  alloc((size_t)BSZ*NTOK*INDIM*2);  // 38.5 MB (unpadded)
    U16*   kvw_bf = (U16*)  alloc((size_t)KVH*INDIM*2);
    U16*   qw_bf  = (U16*)  alloc((size_t)INDIM*INDIM*2);
    U16*   prw_bf = (U16*)  alloc((size_t)OUTD*DHD*2);
    float* s_kv   = (float*)alloc(KVH*4);
    float* b_kv   = (float*)alloc(KVH*4);
    float* s_q    = (float*)alloc(INDIM*4);
    float* b_q    = (float*)alloc(INDIM*4);
    float* s_pr   = (float*)alloc(OUTD*4);
    float* b_pr   = (float*)alloc(OUTD*4);
    float* biasf  = (float*)alloc(((size_t)NH*NQ*NTOK + 256)*4);  // +pad for f4 tail reads
    U16*   a_out  = (U16*)  alloc((size_t)BSZ*NQ*DHD*2);      // 19.3 MB
    if (off > ws_size) return;  // insufficient workspace: fail visibly (no OOB writes)

    // prep (ONE launch: x cast | weight casts | bias + BN)
    k_prep<<<XC_BLK + WC_BLK + BIAS_BLK + BN_BLK, 256, 0, stream>>>(
        x, x_bf, kv_w, q_w, pr_w, kvw_bf, qw_bf, prw_bf,
        ab, idxs, n_off,
        kv_g, kv_b, kv_m, kv_v, q_g, q_b, q_m, q_v, pr_g, pr_b, pr_m, pr_v,
        s_kv, b_kv, s_q, b_q, s_pr, b_pr, biasf);

    // fused kvq-GEMM + attention + hard_swish (1 head/block, XCD-swizzled)
    k_fused<<<BSZ*NH, 256, 0, stream>>>(x_bf, kvw_bf, qw_bf, s_kv, b_kv, s_q, b_q,
                                        biasf, a_out);
    // proj GEMM: (12544 x 512 x 768) -> f32 out
    k_proj<<<784, 256, 0, stream>>>(a_out, prw_bf, s_pr, b_pr, (float*)d_out);
}

// Round 17
// 179.882 us; speedup vs baseline: 1.0848x; 1.0848x over previous
//
#include <hip/hip_runtime.h>
#include <hip/hip_bf16.h>
#include <math.h>

typedef unsigned short U16;
typedef unsigned int U32;
typedef __attribute__((ext_vector_type(8))) short bf8;        // 8 x bf16 (MFMA A/B frag)
typedef __attribute__((ext_vector_type(4))) float f4;         // MFMA C/D frag
typedef __attribute__((ext_vector_type(4))) unsigned short u16x4;

#define AS1 __attribute__((address_space(1)))
#define AS3 __attribute__((address_space(3)))

// ---- constants ----
#define BSZ   256
#define NTOK  196
#define NQ    49
#define INDIM 384
#define OUTD  512
#define NH    12
#define DV    64
#define DHD   768
#define KVH   1152
#define NPADR 224      // LDS token rows (196 real + 28 clamped copies of row 195, masked)

__device__ inline U16 f2bf(float f){
    __hip_bfloat16 h = __float2bfloat16(f);
    return *(U16*)&h;
}
__device__ inline f4 f4zero(){ f4 z; z[0]=0.f; z[1]=0.f; z[2]=0.f; z[3]=0.f; return z; }
__device__ inline bf8 bf8zero(){ bf8 v;
#pragma unroll
    for (int j=0;j<8;++j) v[j]=0; return v; }

// ---------------- single prep kernel: x cast | weight casts | bias + BN ----------------
#define XC_N   (BSZ*NTOK*INDIM/8)    // 2,408,448 slots
#define XC_BLK (XC_N/256)            // 9408 (exact)
#define W1C (KVH*INDIM/8)            // 55296
#define W2C (INDIM*INDIM/8)          // 18432
#define W3C (OUTD*DHD/8)             // 49152
#define WC_N   (W1C+W2C+W3C)         // 122880
#define WC_BLK (WC_N/256)            // 480 (exact)
#define BIAS_N   (NH*NQ*NTOK)        // 115248
#define BIAS_BLK ((BIAS_N+255)/256)  // 451
#define BN_BLK   ((KVH+INDIM+OUTD)/256)  // 8
__global__ void k_prep(const float* __restrict__ x, U16* __restrict__ x_bf,
                       const float* __restrict__ w1, const float* __restrict__ w2,
                       const float* __restrict__ w3, U16* __restrict__ o1,
                       U16* __restrict__ o2, U16* __restrict__ o3,
                       const float* __restrict__ ab, const int* __restrict__ idxs, int n_off,
                       const float* __restrict__ g1, const float* __restrict__ b1,
                       const float* __restrict__ m1, const float* __restrict__ v1,
                       const float* __restrict__ g2, const float* __restrict__ b2,
                       const float* __restrict__ m2, const float* __restrict__ v2,
                       const float* __restrict__ g3, const float* __restrict__ b3,
                       const float* __restrict__ m3, const float* __restrict__ v3,
                       float* __restrict__ s1, float* __restrict__ bo1,
                       float* __restrict__ s2, float* __restrict__ bo2,
                       float* __restrict__ s3, float* __restrict__ bo3,
                       float* __restrict__ bias_out){
    const int blk = blockIdx.x;
    const int tid = threadIdx.x;
    if (blk < XC_BLK){
        int i = blk*256 + tid;                 // 8-elem slot of x
        const float* p = x + (size_t)i*8;
        U16 o[8];
#pragma unroll
        for (int j=0;j<8;++j) o[j] = f2bf(p[j]);
        *(bf8*)(x_bf + (size_t)i*8) = *(const bf8*)o;
    } else if (blk < XC_BLK + WC_BLK){
        int i = (blk-XC_BLK)*256 + tid;
        const float* p; U16* o;
        if (i < W1C){ p = w1 + (size_t)i*8; o = o1 + (size_t)i*8; }
        else if (i < W1C+W2C){ int k=i-W1C; p = w2 + (size_t)k*8; o = o2 + (size_t)k*8; }
        else { int k=i-W1C-W2C; p = w3 + (size_t)k*8; o = o3 + (size_t)k*8; }
        U16 t[8];
#pragma unroll
        for (int j=0;j<8;++j) t[j] = f2bf(p[j]);
        *(bf8*)o = *(const bf8*)t;
    } else if (blk < XC_BLK + WC_BLK + BIAS_BLK){
        int i = (blk-XC_BLK-WC_BLK)*256 + tid;
        if (i < BIAS_N){
            int h = i / (NQ*NTOK);
            int qk = i - h*(NQ*NTOK);
            bias_out[i] = ab[h*n_off + idxs[qk]];
        }
    } else {
        int i = (blk-XC_BLK-WC_BLK-BIAS_BLK)*256 + tid;
        const float *g,*b,*m,*v; float *so,*bo; int k;
        if (i < KVH){ g=g1;b=b1;m=m1;v=v1;so=s1;bo=bo1;k=i; }
        else if (i < KVH+INDIM){ g=g2;b=b2;m=m2;v=v2;so=s2;bo=bo2;k=i-KVH; }
        else { g=g3;b=b3;m=m3;v=v3;so=s3;bo=bo3;k=i-KVH-INDIM; }
        float s = g[k] / sqrtf(v[k] + 1e-5f);
        so[k] = s;
        bo[k] = b[k] - m[k]*s;
    }
}

// ---------------- fused kv-GEMM + attention: 1 head/block, single-barrier K-loop ----------------
// x_bf is UNPADDED [256][196][384]; LDS A rows 196..223 clamp to row 195 (masked downstream).
// GEMM: C[224 rows][96 cols = k(32)|v(64)], BK=32, 12 K-steps, 5 loads/thread/step.
// LDS = 20480 u16 = 40,960 B.
//   staging: A0 [0,7168) A1 [7168,14336) B0 [14336,17408) B1 [17408,20480)
//   post-GEMM (aliases dead staging):
//     VL [0,12800):      [nch<=24][64 d][8] (writes guarded n0<200)
//     KL [12800,19968):  [4 dch][224 n][8]
//     PV reads VL nch 25..27 (n>=200) overlap KL -> finite garbage x P=0 = 0.
// P never hits LDS: cross-lane __shfl transpose into PV A-frags (packed on the fly).
#define KLO 12800
__global__ __launch_bounds__(256,2) void k_fused(
    const U16* __restrict__ xbf, const U16* __restrict__ kvw, const U16* __restrict__ qo_,
    const float* __restrict__ skv, const float* __restrict__ bkv,
    const float* __restrict__ biasf, U16* __restrict__ aout)
{
    __shared__ U16 smem[20480];   // 40,960 B
    const int hw = blockIdx.x;
    const int bh = (hw & 7)*384 + (hw >> 3);   // bijective XCD swizzle (3072 = 8*384)
    const int b = bh / NH, h = bh - b*NH;
    const int tid = threadIdx.x, lane = tid & 63, w = tid >> 6;
    const int wm = w & 1, wn = w >> 1;
    const int l15 = lane & 15, oct = lane >> 4;

    U16* Ab[2] = { smem + 0,     smem + 7168 };
    U16* Bb[2] = { smem + 14336, smem + 17408 };

    // A: 896 chunks (slot = kch*224 + row); threads 0..127 take a 4th; row clamped <196
    U32 aoff[4];
#pragma unroll
    for (int c=0;c<3;++c){
        int s = c*256 + tid;
        int ach = s / NPADR, ar = s - ach*NPADR;
        int row = (ar < NTOK) ? ar : (NTOK-1);
        aoff[c] = (U32)(b*NTOK + row)*INDIM + ach*8;
    }
    {
        int s = 768 + (tid & 127);
        int ach = s / NPADR, ar = s - ach*NPADR;
        int row = (ar < NTOK) ? ar : (NTOK-1);
        aoff[3] = (U32)(b*NTOK + row)*INDIM + ach*8;
    }
    // B: 384 chunks (slot = kch*96 + row); threads >=128 take a 2nd
    U32 boff[2];
    {
        int s0 = tid;
        int bc0 = s0 / 96, br0 = s0 - bc0*96;
        boff[0] = (U32)(h*96 + br0)*INDIM + bc0*8;
        int s1 = 128 + (tid | 128);            // tid>=128 -> 256..383
        int bc1 = s1 / 96, br1 = s1 - bc1*96;
        boff[1] = (U32)(h*96 + br1)*INDIM + bc1*8;
    }

    f4 acc[7][3];
#pragma unroll
    for (int i=0;i<7;++i)
#pragma unroll
        for (int j=0;j<3;++j) acc[i][j] = f4zero();

#define STAGE(buf, kb) do{ \
    _Pragma("unroll") \
    for (int c=0;c<3;++c) \
        __builtin_amdgcn_global_load_lds((const AS1 U32*)(xbf + aoff[c] + (kb)), \
            (AS3 U32*)(Ab[buf] + (c*256+tid)*8), 16, 0, 0); \
    if (tid < 128) \
        __builtin_amdgcn_global_load_lds((const AS1 U32*)(xbf + aoff[3] + (kb)), \
            (AS3 U32*)(Ab[buf] + (768+tid)*8), 16, 0, 0); \
    __builtin_amdgcn_global_load_lds((const AS1 U32*)(kvw + boff[0] + (kb)), \
        (AS3 U32*)(Bb[buf] + tid*8), 16, 0, 0); \
    if (tid >= 128) \
        __builtin_amdgcn_global_load_lds((const AS1 U32*)(kvw + boff[1] + (kb)), \
            (AS3 U32*)(Bb[buf] + (128+tid)*8), 16, 0, 0); \
}while(0)

    // prologue: tile 0 staged and drained
    STAGE(0, 0);
    asm volatile("s_waitcnt vmcnt(0)" ::: "memory");
    __builtin_amdgcn_sched_barrier(0);
    __builtin_amdgcn_s_barrier();
    __builtin_amdgcn_sched_barrier(0);

#pragma unroll
    for (int kt=0; kt<12; ++kt){
        const int cur = kt & 1;
        // stage next tile into the buffer whose reads finished before the last barrier
        if (kt < 11) STAGE(cur^1, (kt+1)*32);
        __builtin_amdgcn_sched_barrier(0);
        bf8 af[7], bfr[3];
#pragma unroll
        for (int i=0;i<7;++i)
            af[i]  = *(const bf8*)(Ab[cur] + (oct*NPADR + wm*112 + i*16 + l15)*8);
#pragma unroll
        for (int j=0;j<3;++j)
            bfr[j] = *(const bf8*)(Bb[cur] + (oct*96 + wn*48 + j*16 + l15)*8);
        __builtin_amdgcn_s_setprio(1);
#pragma unroll
        for (int i=0;i<7;++i)
#pragma unroll
            for (int j=0;j<3;++j)
                acc[i][j] = __builtin_amdgcn_mfma_f32_16x16x32_bf16(af[i], bfr[j], acc[i][j], 0, 0, 0);
        __builtin_amdgcn_s_setprio(0);
        __builtin_amdgcn_sched_barrier(0);
        asm volatile("s_waitcnt vmcnt(0)" ::: "memory");   // next tile landed (drain hidden under MFMA)
        __builtin_amdgcn_s_barrier();                      // ONE barrier per step
        __builtin_amdgcn_sched_barrier(0);
    }
#undef STAGE

    // ---- epilogue: BN fold, scatter acc -> VL/KL (alias dead staging) ----
#pragma unroll
    for (int j=0;j<3;++j){
        const int cc = wn*48 + j*16 + l15;
        const float sc = skv[h*96 + cc];
        const float bi = bkv[h*96 + cc];
#pragma unroll
        for (int i=0;i<7;++i){
            const int n0 = wm*112 + i*16 + oct*4;
            if (cc < 32){
#pragma unroll
                for (int r=0;r<4;++r)
                    smem[KLO + ((cc>>3)*NPADR + n0 + r)*8 + (cc&7)] = f2bf(acc[i][j][r]*sc + bi);
            } else if (n0 < 200){
                const int dv = cc - 32;
                u16x4 pk;
#pragma unroll
                for (int r=0;r<4;++r) pk[r] = f2bf(acc[i][j][r]*sc + bi);
                *(u16x4*)(smem + ((n0>>3)*64 + dv)*8 + (oct&1)*4) = pk;
            }
        }
    }
    __syncthreads();

    const int qg = w*16 + l15;
    bf8 qf = bf8zero();
    if (qg < NQ) qf = *(const bf8*)(qo_ + ((size_t)(b*NQ + qg))*INDIM + h*32 + oct*8);

    f4 sacc[14];
#pragma unroll
    for (int mt=0;mt<14;++mt) sacc[mt] = f4zero();
#pragma unroll
    for (int mt=0;mt<14;++mt){
        const bf8 kf = *(const bf8*)(smem + KLO + (oct*NPADR + mt*16 + l15)*8);
        sacc[mt] = __builtin_amdgcn_mfma_f32_16x16x32_bf16(kf, qf, sacc[mt], 0, 0, 0);
    }

    const float scale = 0.17677669529663689f;
    float mx = -1e30f;
#pragma unroll
    for (int mt=0;mt<14;++mt){
        const int n0 = mt*16 + oct*4;
        f4 bi4 = f4zero();
        if (qg < NQ && n0 < NTOK) bi4 = *(const f4*)(biasf + ((size_t)h*NQ + qg)*NTOK + n0);
#pragma unroll
        for (int r=0;r<4;++r){
            float s = (n0 + r < NTOK) ? sacc[mt][r]*scale + bi4[r] : -1e30f;
            sacc[mt][r] = s;
            mx = fmaxf(mx, s);
        }
    }
    mx = fmaxf(mx, __shfl_xor(mx, 16));
    mx = fmaxf(mx, __shfl_xor(mx, 32));

    float sum = 0.f;
#pragma unroll
    for (int mt=0;mt<14;++mt){
#pragma unroll
        for (int r=0;r<4;++r){
            float p = (mt*16 + oct*4 + r < NTOK) ? __expf(sacc[mt][r] - mx) : 0.f;
            sacc[mt][r] = p;
            sum += p;
        }
    }
    sum += __shfl_xor(sum, 16);
    sum += __shfl_xor(sum, 32);
    const float inv = 1.f / sum;

    const int src1 = l15 + (oct & 1)*32;
    const int src2 = src1 + 16;
    const bool hiT = (oct >> 1) != 0;
    f4 pacc[4];
#pragma unroll
    for (int dt=0;dt<4;++dt) pacc[dt] = f4zero();
#pragma unroll
    for (int kt=0;kt<7;++kt){
        const int m0 = 2*kt, m1 = 2*kt+1;
        U32 q00 = (U32)f2bf(sacc[m0][0]*inv) | ((U32)f2bf(sacc[m0][1]*inv) << 16);
        U32 q01 = (U32)f2bf(sacc[m0][2]*inv) | ((U32)f2bf(sacc[m0][3]*inv) << 16);
        U32 q10 = (U32)f2bf(sacc[m1][0]*inv) | ((U32)f2bf(sacc[m1][1]*inv) << 16);
        U32 q11 = (U32)f2bf(sacc[m1][2]*inv) | ((U32)f2bf(sacc[m1][3]*inv) << 16);
        U32 a0 = __shfl(q00, src1), a1 = __shfl(q01, src1);
        U32 c0 = __shfl(q10, src1), c1 = __shfl(q11, src1);
        U32 b0 = __shfl(q00, src2), b1 = __shfl(q01, src2);
        U32 d0 = __shfl(q10, src2), d1 = __shfl(q11, src2);
        union { U32 u[4]; bf8 v; } pu;
        pu.u[0] = hiT ? c0 : a0;
        pu.u[1] = hiT ? c1 : a1;
        pu.u[2] = hiT ? d0 : b0;
        pu.u[3] = hiT ? d1 : b1;
#pragma unroll
        for (int dt=0;dt<4;++dt){
            const bf8 vf = *(const bf8*)(smem + ((kt*4 + oct)*64 + dt*16 + l15)*8);
            pacc[dt] = __builtin_amdgcn_mfma_f32_16x16x32_bf16(pu.v, vf, pacc[dt], 0, 0, 0);
        }
    }

#pragma unroll
    for (int dt=0;dt<4;++dt){
#pragma unroll
        for (int r=0;r<4;++r){
            const int qo2 = w*16 + oct*4 + r;
            if (qo2 < NQ){
                const int d = dt*16 + l15;
                float v = pacc[dt][r];
                float tt = fminf(fmaxf(v + 3.f, 0.f), 6.f);
                aout[((size_t)(b*NQ + qo2))*DHD + h*DV + d] = f2bf(v * tt * (1.f/6.f));
            }
        }
    }
}

// ---------------- 128x64xBK64 GEMM template (qgemm + proj), 3 blocks/CU ----------------
// EPI 0: bf16 out (stride INDIM)   EPI 1: f32 out (stride OUTD)
// SUB: A rows are subsampled token rows of UNPADDED x_bf.
template<int EPI, int NK, int KD, int NTILN, int NWG, bool SUB>
__global__ __launch_bounds__(256,2) void k_g64(
    const U16* __restrict__ A, const U16* __restrict__ Bw,
    const float* __restrict__ s_arr, const float* __restrict__ b_arr,
    U16* __restrict__ o16, float* __restrict__ o32)
{
    __shared__ U16 smem[24576];
    U16* Ab[2] = { smem,          smem + 8192 };
    U16* Bb[2] = { smem + 16384,  smem + 20480 };
    constexpr int QQ = NWG/8, RR = NWG%8;
    const int xcd = blockIdx.x & 7, rest = blockIdx.x >> 3;
    const int l = (xcd < RR ? xcd*(QQ+1) : RR*(QQ+1) + (xcd-RR)*QQ) + rest;
    const int mtl = l / NTILN, ntl = l - mtl*NTILN;
    const int gm0 = mtl*128, gn0 = ntl*64;
    const int tid  = threadIdx.x;
    const int lane = tid & 63;
    const int w    = tid >> 6;
    const int wm   = w & 1, wn = w >> 1;
    const int l15  = lane & 15, oct = lane >> 4;

    f4 acc[4][2];
#pragma unroll
    for (int i=0;i<4;++i)
#pragma unroll
        for (int j=0;j<2;++j) acc[i][j] = f4zero();

    U32 aoff[4], boff[2];
#pragma unroll
    for (int c=0;c<4;++c){
        int slot = c*256 + tid;
        int row = slot & 127, ch = slot >> 7;
        int grow = gm0 + row;
        if (SUB){
            int b2 = grow / NQ, qq = grow - b2*NQ;
            grow = b2*NTOK + 28*(qq/7) + 2*(qq%7);
        }
        aoff[c] = (U32)grow*KD + ch*8;
    }
#pragma unroll
    for (int c=0;c<2;++c){
        int slot = c*256 + tid;
        int row = slot & 63, ch = slot >> 6;
        boff[c] = (U32)(gn0 + row)*KD + ch*8;
    }

#define STG(buf, kb) do{ \
    _Pragma("unroll") \
    for (int c=0;c<4;++c) \
        __builtin_amdgcn_global_load_lds((const AS1 U32*)(A + aoff[c] + (kb)), \
            (AS3 U32*)(Ab[buf] + (c*256+tid)*8), 16, 0, 0); \
    _Pragma("unroll") \
    for (int c=0;c<2;++c) \
        __builtin_amdgcn_global_load_lds((const AS1 U32*)(Bw + boff[c] + (kb)), \
            (AS3 U32*)(Bb[buf] + (c*256+tid)*8), 16, 0, 0); \
}while(0)

    STG(0, 0);

#pragma unroll
    for (int kt=0; kt<NK; ++kt){
        const int cur = kt & 1;
        if (kt+1 < NK){
            STG(cur^1, (kt+1)*64);
            asm volatile("s_waitcnt vmcnt(6)" ::: "memory");
        } else {
            asm volatile("s_waitcnt vmcnt(0)" ::: "memory");
        }
        __builtin_amdgcn_sched_barrier(0);
        __builtin_amdgcn_s_barrier();
        __builtin_amdgcn_sched_barrier(0);

#pragma unroll
        for (int kk=0;kk<2;++kk){
            bf8 af[4], bfr[2];
#pragma unroll
            for (int i=0;i<4;++i)
                af[i]  = *(const bf8*)(Ab[cur] + ((kk*4+oct)*128 + wm*64 + i*16 + l15)*8);
#pragma unroll
            for (int j=0;j<2;++j)
                bfr[j] = *(const bf8*)(Bb[cur] + ((kk*4+oct)*64 + wn*32 + j*16 + l15)*8);
            __builtin_amdgcn_s_setprio(1);
#pragma unroll
            for (int i=0;i<4;++i)
#pragma unroll
                for (int j=0;j<2;++j)
                    acc[i][j] = __builtin_amdgcn_mfma_f32_16x16x32_bf16(af[i], bfr[j], acc[i][j], 0, 0, 0);
            __builtin_amdgcn_s_setprio(0);
        }
        __builtin_amdgcn_sched_barrier(0);
        __builtin_amdgcn_s_barrier();
        __builtin_amdgcn_sched_barrier(0);
    }
#undef STG

#pragma unroll
    for (int j=0;j<2;++j){
        const int col = gn0 + wn*32 + j*16 + l15;
        const float sc = s_arr[col];
        const float bi = b_arr[col];
#pragma unroll
        for (int i=0;i<4;++i){
            const int row0 = gm0 + wm*64 + i*16 + oct*4;
#pragma unroll
            for (int r=0;r<4;++r){
                const float val = acc[i][j][r]*sc + bi;
                if (EPI == 0) o16[(size_t)(row0+r)*INDIM + col] = f2bf(val);
                else          o32[(size_t)(row0+r)*OUTD  + col] = val;
            }
        }
    }
}

// ---------------- launch ----------------
extern "C" void kernel_launch(void* const* d_in, const int* in_sizes, int n_in,
                              void* d_out, int out_size, void* d_ws, size_t ws_size,
                              hipStream_t stream)
{
    const float* x    = (const float*)d_in[0];
    const float* kv_w = (const float*)d_in[1];
    const float* kv_g = (const float*)d_in[2];
    const float* kv_b = (const float*)d_in[3];
    const float* kv_m = (const float*)d_in[4];
    const float* kv_v = (const float*)d_in[5];
    const float* q_w  = (const float*)d_in[6];
    const float* q_g  = (const float*)d_in[7];
    const float* q_b  = (const float*)d_in[8];
    const float* q_m  = (const float*)d_in[9];
    const float* q_v  = (const float*)d_in[10];
    const float* pr_w = (const float*)d_in[11];
    const float* pr_g = (const float*)d_in[12];
    const float* pr_b = (const float*)d_in[13];
    const float* pr_m = (const float*)d_in[14];
    const float* pr_v = (const float*)d_in[15];
    const float* ab   = (const float*)d_in[16];
    const int*  idxs  = (const int*)d_in[17];
    const int n_off = in_sizes[16] / NH;

    char* ws = (char*)d_ws;
    size_t off = 0;
    auto alloc = [&](size_t bytes)->char*{
        char* p = ws + off; off += (bytes + 255) & ~(size_t)255; return p;
    };
    U16*   x_bf   = (U16*)  alloc((size_t)BSZ*NTOK*INDIM*2);  // 38.5 MB (unpadded)
    U16*   kvw_bf = (U16*)  alloc((size_t)KVH*INDIM*2);
    U16*   qw_bf  = (U16*)  alloc((size_t)INDIM*INDIM*2);
    U16*   prw_bf = (U16*)  alloc((size_t)OUTD*DHD*2);
    float* s_kv   = (float*)alloc(KVH*4);
    float* b_kv   = (float*)alloc(KVH*4);
    float* s_q    = (float*)alloc(INDIM*4);
    float* b_q    = (float*)alloc(INDIM*4);
    float* s_pr   = (float*)alloc(OUTD*4);
    float* b_pr   = (float*)alloc(OUTD*4);
    float* biasf  = (float*)alloc(((size_t)NH*NQ*NTOK + 256)*4);  // +pad for f4 tail reads
    U16*   q_out  = (U16*)  alloc((size_t)BSZ*NQ*INDIM*2);    // 9.6 MB
    U16*   a_out  = (U16*)  alloc((size_t)BSZ*NQ*DHD*2);      // 19.3 MB
    if (off > ws_size) return;  // insufficient workspace: fail visibly (no OOB writes)

    // prep (ONE launch: x cast | weight casts | bias + BN)
    k_prep<<<XC_BLK + WC_BLK + BIAS_BLK + BN_BLK, 256, 0, stream>>>(
        x, x_bf, kv_w, q_w, pr_w, kvw_bf, qw_bf, prw_bf,
        ab, idxs, n_off,
        kv_g, kv_b, kv_m, kv_v, q_g, q_b, q_m, q_v, pr_g, pr_b, pr_m, pr_v,
        s_kv, b_kv, s_q, b_q, s_pr, b_pr, biasf);

    // q GEMM: (12544 x 384 x 384), A = subsampled rows of x_bf -> bf16 q_out
    k_g64<0, 6, INDIM, 6, 588, true><<<588, 256, 0, stream>>>(
        x_bf, qw_bf, s_q, b_q, q_out, nullptr);
    // fused kv-GEMM + attention + hard_swish (1 head/block, XCD-swizzled, 1-barrier K-loop)
    k_fused<<<BSZ*NH, 256, 0, stream>>>(x_bf, kvw_bf, q_out, s_kv, b_kv, biasf, a_out);
    // proj GEMM: (12544 x 512 x 768) -> f32 out
    k_g64<1, 12, DHD, 8, 784, false><<<784, 256, 0, stream>>>(
        a_out, prw_bf, s_pr, b_pr, nullptr, (float*)d_out);
}